// Round 16
// baseline (254.908 us; speedup 1.0000x reference)
//
#include <hip/hip_runtime.h>
#include <hip/hip_bf16.h>
#include <math.h>

// Layout constants: B=2, C=64, T=16, H=W=64, S=3, r=4
// x: ((b*64+c)*16+t)*4096 + h*64+w ; frame n in [0,32): b=n>>4, t=n&15
// xT bf16: [n][h 0..63][w' 0..65][c 0..63], w'=w+1, cols 0/65 zero. frame stride 270336, row stride 4224
// hidden bf16: [n][r 0..63][px' 0..65][co 0..63], pad cols zero (written by conv1 epilogue).
// conv1 weights (Wb): per side, per tap: 64co x 128ci bf16, SWIZZLED: el = co*128 + (ci ^ ((co&15)<<3))

typedef __attribute__((ext_vector_type(8))) short short8v;
typedef __attribute__((ext_vector_type(4))) float f32x4;

#define HID_ELEMS 8650752ULL

__device__ __forceinline__ float sigmoidf_(float v) {
    return 1.0f / (1.0f + expf(-v));
}

__device__ __forceinline__ float bf2f(short s) {
    union { unsigned u; float f; } z;
    z.u = ((unsigned)(unsigned short)s) << 16;
    return z.f;
}

// async global->LDS, 16B per lane; LDS base must be wave-uniform (HW adds lane*16)
__device__ __forceinline__ void gll16(const __hip_bfloat16* g, __hip_bfloat16* l) {
    __builtin_amdgcn_global_load_lds((const __attribute__((address_space(1))) unsigned int*)(const void*)g,
                                     (__attribute__((address_space(3))) unsigned int*)(void*)l,
                                     16, 0, 0);
}

// load one tl's 8 A-fragments (2 khalf x {mi0ks0, mi0ks1, mi1ks0, mi1ks1})
__device__ __forceinline__ void load_afrag(const __hip_bfloat16* r0, const __hip_bfloat16* r1,
                                           int abase, short8v* dst) {
    dst[0] = *(const short8v*)(r0 + abase);
    dst[1] = *(const short8v*)(r0 + abase + 32);
    dst[2] = *(const short8v*)(r0 + abase + 1024);
    dst[3] = *(const short8v*)(r0 + abase + 1056);
    dst[4] = *(const short8v*)(r1 + abase);
    dst[5] = *(const short8v*)(r1 + abase + 32);
    dst[6] = *(const short8v*)(r1 + abase + 1024);
    dst[7] = *(const short8v*)(r1 + abase + 1056);
}

// Bilinear sample setup matching reference grid_sample semantics; offsets in xT/channel-last coords.
struct Samp { int o0, o1, o2, o3; float w0, w1, w2, w3; };

__device__ __forceinline__ Samp make_samp(float ox, float oy, int w, int h) {
    float bx = (2.0f * (float)w) / 63.0f - 1.0f;
    float by = (2.0f * (float)h) / 63.0f - 1.0f;
    float vx = bx + ox / 63.0f;
    float vy = by + oy / 63.0f;
    float gx = ((vx + 1.0f) * 64.0f - 1.0f) * 0.5f;
    float gy = ((vy + 1.0f) * 64.0f - 1.0f) * 0.5f;
    float fx = floorf(gx), fy = floorf(gy);
    float wx = gx - fx, wy = gy - fy;
    int x0 = (int)fx, y0 = (int)fy;
    int x1 = x0 + 1, y1 = y0 + 1;
    bool vx0 = (x0 >= 0) && (x0 < 64), vx1 = (x1 >= 0) && (x1 < 64);
    bool vy0 = (y0 >= 0) && (y0 < 64), vy1 = (y1 >= 0) && (y1 < 64);
    int cx0 = min(max(x0, 0), 63), cx1 = min(max(x1, 0), 63);
    int cy0 = min(max(y0, 0), 63), cy1 = min(max(y1, 0), 63);
    Samp s;
    s.o0 = cy0 * 4224 + (cx0 + 1) * 64; s.w0 = (1.0f - wx) * (1.0f - wy) * ((vx0 && vy0) ? 1.0f : 0.0f);
    s.o1 = cy0 * 4224 + (cx1 + 1) * 64; s.w1 = wx * (1.0f - wy) * ((vx1 && vy0) ? 1.0f : 0.0f);
    s.o2 = cy1 * 4224 + (cx0 + 1) * 64; s.w2 = (1.0f - wx) * wy * ((vx0 && vy1) ? 1.0f : 0.0f);
    s.o3 = cy1 * 4224 + (cx1 + 1) * 64; s.w3 = wx * wy * ((vx1 && vy1) ? 1.0f : 0.0f);
    return s;
}

// ---------- prep: x fp32 -> xT bf16 channel-last padded; fused down conv; fused weight prep ----------
__global__ __launch_bounds__(256) void k_prep_x(const float* __restrict__ x,
                                                const float* __restrict__ dw,
                                                const float* __restrict__ wl1,
                                                const float* __restrict__ wr1,
                                                const float* __restrict__ wl2,
                                                const float* __restrict__ wr2,
                                                __hip_bfloat16* __restrict__ xT,
                                                float* __restrict__ xa,
                                                __hip_bfloat16* __restrict__ Wmisc)
{
    int bid = blockIdx.x;          // 2048 = n*64 + h
    int h = bid & 63;
    int n = bid >> 6;
    int b = n >> 4, t = n & 15;
    __shared__ float s[64][65];
    int tid = threadIdx.x;
    for (int idx = tid; idx < 4096; idx += 256) {
        int c = idx >> 6, w = idx & 63;
        s[c][w] = x[(((size_t)b * 64 + c) * 16 + t) * 4096 + h * 64 + w];
    }
    __syncthreads();
    __hip_bfloat16* op = xT + ((size_t)n * 64 + h) * 4224;
    for (int idx = tid; idx < 4224; idx += 256) {
        int wp = idx >> 6, c = idx & 63;
        float v = (wp == 0 || wp == 65) ? 0.f : s[c][wp - 1];
        op[idx] = __float2bfloat16(v);
    }
    // fused down conv: per (g, w) dot over c
    int w = tid & 63, g = tid >> 6;
    float acc = 0.f;
    const float* dwg = dw + g * 64;
    #pragma unroll 8
    for (int c = 0; c < 64; c++) acc = fmaf(s[c][w], dwg[c], acc);
    xa[((size_t)(b * 4 + g) * 16 + t) * 4096 + h * 64 + w] = acc;

    // fused weight prep (blocks 0..664 cover 170112 elements)
    int idx = bid * 256 + tid;
    if (idx < 147456) {
        // conv1: [side][tap 9][co 64][ci 128], ci position XOR-swizzled for LDS bank spread
        int side = (idx >= 73728) ? 1 : 0;
        int i = idx - side * 73728;
        int ci = i & 127;
        int co = (i >> 7) & 63;
        int tap = i >> 13;
        const float* wsrc = side ? wr1 : wl1;
        float v = wsrc[((size_t)co * 128 + ci) * 9 + tap];
        int pos = side * 73728 + tap * 8192 + co * 128 + (ci ^ ((co & 15) << 3));
        Wmisc[pos] = __float2bfloat16(v);
    } else if (idx < 151680) {
        Wmisc[idx] = __float2bfloat16(0.f);      // zero row (4224)
    } else if (idx < 170112) {
        // conv2: [side][tap 9][co 16 pad][ci 64]
        int i2 = idx - 151680;
        int side = i2 / 9216;
        int j = i2 - side * 9216;
        int tap = j >> 10;
        int rem = j & 1023;
        int co = rem >> 6;
        int ci = rem & 63;
        const float* wsrc = side ? wr2 : wl2;
        float v = (co < 6) ? wsrc[((size_t)co * 64 + ci) * 9 + tap] : 0.f;
        Wmisc[idx] = __float2bfloat16(v);
    }
}

// compute one tl slice: 32 MFMAs from A regs + LDS B
#define COMPUTE_TL(TL, A) \
    _Pragma("unroll") \
    for (int khalf = 0; khalf < 2; khalf++) { \
        _Pragma("unroll") \
        for (int ni = 0; ni < 4; ni++) { \
            int rowb = (TL) * 16384 + ni * 4096 + lr * 256; \
            short8v b0  = *(const short8v*)(sbc + (rowb + kx[khalf][0])); \
            short8v b1v = *(const short8v*)(sbc + (rowb + kx[khalf][1])); \
            acc[0][ni] = __builtin_amdgcn_mfma_f32_16x16x32_bf16((A)[khalf*4+0], b0,  acc[0][ni], 0, 0, 0); \
            acc[1][ni] = __builtin_amdgcn_mfma_f32_16x16x32_bf16((A)[khalf*4+2], b0,  acc[1][ni], 0, 0, 0); \
            acc[0][ni] = __builtin_amdgcn_mfma_f32_16x16x32_bf16((A)[khalf*4+1], b1v, acc[0][ni], 0, 0, 0); \
            acc[1][ni] = __builtin_amdgcn_mfma_f32_16x16x32_bf16((A)[khalf*4+3], b1v, acc[1][ni], 0, 0, 0); \
        } \
    }

// ---------- conv1 via MFMA: 128->64 3x3 pad1 + ReLU; 3-tap kh-group LDS staging ----------
// grid 512 (one side, swz=0) or 1024 (both, swz=1 XCD-frame-affine). 512 thr = 8 waves.
// swz mapping (bijective, 1024 blocks): bid = (n&7) + 8*((n>>3)*32 + side*16 + rq)
// -> all 32 blocks of frame n land on XCD n&7; per-XCD working set ~3 frames ~2.2MB < 4MB L2.
__global__ __launch_bounds__(512, 4) void k_conv1_mfma(const __hip_bfloat16* __restrict__ xT,
                                                       const __hip_bfloat16* __restrict__ Wb,
                                                       const __hip_bfloat16* __restrict__ zrow,
                                                       const float* __restrict__ b1l,
                                                       const float* __restrict__ b1r,
                                                       __hip_bfloat16* __restrict__ hidden,
                                                       int side_base, size_t hid_stride, int swz)
{
    __shared__ __hip_bfloat16 sB[24576];         // 48KB: 3 taps x (64co x 128ci)

    int bid = blockIdx.x;
    int side, rq, n;
    if (swz) {
        int xcd = bid & 7;
        int k = bid >> 3;
        n = xcd + ((k >> 5) << 3);
        side = (k >> 4) & 1;
        rq = k & 15;
    } else {
        side = side_base + (bid >> 9);
        int bid2 = bid & 511;
        rq = bid2 & 15;
        n = bid2 >> 4;
    }
    int b = n >> 4, t = n & 15;
    int t2 = side ? max(t - 1, 0) : min(t + 1, 15);
    int n2 = b * 16 + t2;

    const __hip_bfloat16* WbS = Wb + (size_t)side * 73728;
    const float* b1 = side ? b1r : b1l;
    __hip_bfloat16* hs = hidden + (size_t)side * hid_stride;

    int tid = threadIdx.x;
    int wv = tid >> 6;
    int lane = tid & 63;
    int r = rq * 4 + (wv & 3);
    int m0 = (wv >> 2) * 32;
    int lr = lane & 15;
    int q = lane >> 4;           // 0..3
    int lk = q << 3;

    const __hip_bfloat16* fA0 = xT + (size_t)n * 270336;
    const __hip_bfloat16* fA1 = xT + (size_t)n2 * 270336;

    f32x4 acc[2][4];
    #pragma unroll
    for (int ni = 0; ni < 4; ni++) {
        float bb = b1[ni * 16 + lr];
        acc[0][ni] = (f32x4){bb, bb, bb, bb};
        acc[1][ni] = (f32x4){bb, bb, bb, bb};
    }

    // swizzled byte offsets within a co-row: (khalf*128 + ks*64 + q*16) ^ (lr<<4)
    int kx[2][2];
    #pragma unroll
    for (int khalf = 0; khalf < 2; khalf++)
        #pragma unroll
        for (int ks = 0; ks < 2; ks++)
            kx[khalf][ks] = ((khalf << 7) + (ks << 6) + (q << 4)) ^ (lr << 4);

    const char* sbc = (const char*)&sB[0];
    int ab0 = (m0 + lr) * 64 + lk;

    short8v A0[8], A1[8], A2[8];

    #pragma unroll
    for (int g = 0; g < 3; g++) {
        int rr = r + g - 1;
        bool ok = (rr >= 0) && (rr < 64);
        const __hip_bfloat16* r0 = ok ? (fA0 + rr * 4224) : zrow;
        const __hip_bfloat16* r1 = ok ? (fA1 + rr * 4224) : zrow;

        __syncthreads();           // previous group fully consumed
        {
            const __hip_bfloat16* wsrc = WbS + (size_t)g * 24576 + wv * 3072 + lane * 8;
            #pragma unroll
            for (int j = 0; j < 6; j++)
                gll16(wsrc + j * 512, &sB[wv * 3072 + j * 512]);
        }
        load_afrag(r0, r1, ab0, A0);            // tl=0 A-loads fly with the staging
        __builtin_amdgcn_sched_barrier(0);
        __syncthreads();                        // vmcnt(0) drains staging + A0 together

        load_afrag(r0, r1, ab0 + 64, A1);       // tl=1: issue now, hide under compute of tl=0
        __builtin_amdgcn_sched_barrier(0);
        COMPUTE_TL(0, A0)
        load_afrag(r0, r1, ab0 + 128, A2);      // tl=2: issue now, hide under compute of tl=1
        __builtin_amdgcn_sched_barrier(0);
        COMPUTE_TL(1, A1)
        COMPUTE_TL(2, A2)
    }

    // store ReLU'd bf16 into padded channel-last hidden (cached stores: conv2 re-reads from L2)
    int pxq = q << 2;
    __hip_bfloat16* hb = hs + (size_t)(n * 64 + r) * 4224;
    #pragma unroll
    for (int mi = 0; mi < 2; mi++) {
        #pragma unroll
        for (int ni = 0; ni < 4; ni++) {
            int co = ni * 16 + lr;
            #pragma unroll
            for (int j = 0; j < 4; j++) {
                int px = m0 + mi * 16 + pxq + j;
                float v = acc[mi][ni][j];
                v = v < 0.f ? 0.f : v;
                hb[(size_t)(px + 1) * 64 + co] = __float2bfloat16(v);
            }
        }
    }
    // zero the pad columns px'=0,65 for this block's 4 rows (one element per thread)
    {
        int row_l = tid >> 7;            // 0..3
        int sel = (tid >> 6) & 1;        // 0 -> px'=0, 1 -> px'=65
        int co = tid & 63;
        hs[(size_t)(n * 64 + rq * 4 + row_l) * 4224 + (sel ? 65 : 0) * 64 + co] = __float2bfloat16(0.f);
    }
}

// ---------- conv2 via MFMA: 64->6 3x3 pad1, M=64 x N=16(6) x K=576 per row ----------
// grid 512 (one side) or 1024 (both); bid = side*512 + n*16 + rq
__global__ __launch_bounds__(256) void k_conv2_mfma(const __hip_bfloat16* __restrict__ hidden,
                                                    const __hip_bfloat16* __restrict__ W2b,
                                                    const __hip_bfloat16* __restrict__ zrow,
                                                    const float* __restrict__ b2l,
                                                    const float* __restrict__ b2r,
                                                    float* __restrict__ off,
                                                    int side_base, size_t hid_stride)
{
    int bid = blockIdx.x;
    int side = side_base + (bid >> 9);
    int bid2 = bid & 511;
    int rq = bid2 & 15;
    int n = bid2 >> 4;
    int tid = threadIdx.x;
    int wv = tid >> 6;
    int lane = tid & 63;
    int r = rq * 4 + wv;
    int lr = lane & 15;
    int lk = (lane >> 4) << 3;

    const __hip_bfloat16* W2bS = W2b + (size_t)side * 9216;
    const float* b2 = side ? b2r : b2l;
    float* offS = off + (size_t)side * 786432;
    const __hip_bfloat16* hbase = hidden + (size_t)side * hid_stride + (size_t)n * 270336;

    float bb = (lr < 6) ? b2[lr] : 0.f;
    f32x4 acc[4];
    #pragma unroll
    for (int mi = 0; mi < 4; mi++) acc[mi] = (f32x4){bb, bb, bb, bb};

    #pragma unroll
    for (int tap = 0; tap < 9; tap++) {
        const int kh = tap / 3, kw = tap - (tap / 3) * 3;
        int rr = r + kh - 1;
        bool ok = (rr >= 0) && (rr < 64);
        const __hip_bfloat16* hr = ok ? (hbase + (size_t)rr * 4224) : zrow;
        const __hip_bfloat16* bw = W2bS + ((size_t)tap * 16 + lr) * 64 + lk;
        short8v b0 = *(const short8v*)(bw);
        short8v b1v = *(const short8v*)(bw + 32);
        #pragma unroll
        for (int mi = 0; mi < 4; mi++) {
            int abase = (mi * 16 + lr + kw) * 64 + lk;
            short8v a0 = *(const short8v*)(hr + abase);
            short8v a1 = *(const short8v*)(hr + abase + 32);
            acc[mi] = __builtin_amdgcn_mfma_f32_16x16x32_bf16(a0, b0, acc[mi], 0, 0, 0);
            acc[mi] = __builtin_amdgcn_mfma_f32_16x16x32_bf16(a1, b1v, acc[mi], 0, 0, 0);
        }
    }
    if (lr < 6) {
        int pxq = (lane >> 4) << 2;
        #pragma unroll
        for (int mi = 0; mi < 4; mi++) {
            #pragma unroll
            for (int j = 0; j < 4; j++) {
                int px = mi * 16 + pxq + j;
                offS[((size_t)n * 6 + lr) * 4096 + r * 64 + px] = acc[mi][j];
            }
        }
    }
}

// ---------- grouped dilated 3D convs, 3 scales, weighted sum (known-good form) ----------
__global__ __launch_bounds__(256) void k_agg(const float* __restrict__ xa,
                                             const float* __restrict__ w1, const float* __restrict__ b1,
                                             const float* __restrict__ w2, const float* __restrict__ b2,
                                             const float* __restrict__ w3, const float* __restrict__ b3,
                                             const float* __restrict__ aw,
                                             float* __restrict__ agg)
{
    int gid = blockIdx.x * 256 + threadIdx.x;   // 524288
    int hw = gid & 4095;
    int rest = gid >> 12;
    int t = rest & 15;
    int g = (rest >> 4) & 3;
    int b = rest >> 6;
    int h = hw >> 6, w = hw & 63;
    const float* base = xa + ((size_t)(b * 4 + g) * 16) * 4096;
    const float* ws0 = w1 + g * 81;
    const float* ws1 = w2 + g * 81;
    const float* ws2 = w3 + g * 81;
    float acc0 = b1[g], acc1 = b2[g], acc2 = b3[g];
    for (int kd = 0; kd < 9; kd++) {
        int d = t + kd - 4;
        if (d < 0 || d > 15) continue;
        const float* fr = base + (size_t)d * 4096;
        #pragma unroll
        for (int kh = 0; kh < 3; kh++) {
            #pragma unroll
            for (int kw = 0; kw < 3; kw++) {
                int widx = kd * 9 + kh * 3 + kw;
                {
                    int yy = h + (kh - 1), xx = w + (kw - 1);
                    if (yy >= 0 && yy < 64 && xx >= 0 && xx < 64)
                        acc0 = fmaf(fr[yy * 64 + xx], ws0[widx], acc0);
                }
                {
                    int yy = h + (kh - 1) * 2, xx = w + (kw - 1) * 2;
                    if (yy >= 0 && yy < 64 && xx >= 0 && xx < 64)
                        acc1 = fmaf(fr[yy * 64 + xx], ws1[widx], acc1);
                }
                {
                    int yy = h + (kh - 1) * 3, xx = w + (kw - 1) * 3;
                    if (yy >= 0 && yy < 64 && xx >= 0 && xx < 64)
                        acc2 = fmaf(fr[yy * 64 + xx], ws2[widx], acc2);
                }
            }
        }
    }
    agg[gid] = acc0 * aw[0] + acc1 * aw[1] + acc2 * aw[2];
}

// ---------- deformable correlation L+R, quarter-split, 2-deep load pipeline ----------
// grid 4096 x 256: wave = 16 pixels x 4 channel-quarters (lane&15 = pixel, lane>>4 = cq)
__global__ __launch_bounds__(256, 4) void k_corr2(const __hip_bfloat16* __restrict__ xT,
                                                  const float* __restrict__ off_l,
                                                  const float* __restrict__ off_r,
                                                  float* __restrict__ stats_l,
                                                  float* __restrict__ stats_r)
{
    int tid = threadIdx.x;
    int wv = tid >> 6;
    int lane = tid & 63;
    int pl = lane & 15;
    int cq = lane >> 4;                          // channel quarter 0..3
    int pidx = blockIdx.x * 64 + wv * 16 + pl;   // 262144 pixel-work items
    int half = pidx >> 17;                       // 0 = left(+1), 1 = right(-1)
    int gid = pidx & 131071;
    const float* off = half ? off_r : off_l;
    float* stats = half ? stats_r : stats_l;

    int hw = gid & 4095;
    int n = gid >> 12;
    int b = n >> 4, t = n & 15;
    int t2 = half ? max(t - 1, 0) : min(t + 1, 15);
    int n2 = b * 16 + t2;
    int h = hw >> 6, w = hw & 63;
    int cc0 = cq * 16;

    const __hip_bfloat16* xf = xT + (size_t)n * 270336 + h * 4224 + (w + 1) * 64 + cc0;
    const __hip_bfloat16* yf = xT + (size_t)n2 * 270336 + cc0;

    Samp sp[3];
    #pragma unroll
    for (int s = 0; s < 3; s++) {
        float ox = off[((size_t)n * 6 + 2 * s) * 4096 + hw];
        float oy = off[((size_t)n * 6 + 2 * s + 1) * 4096 + hw];
        sp[s] = make_samp(ox, oy, w, h);
    }

    // x fragment
    short8v xv0 = *(const short8v*)(xf);
    short8v xv1 = *(const short8v*)(xf + 8);

    int o0[4] = {sp[0].o0, sp[0].o1, sp[0].o2, sp[0].o3};
    int o1[4] = {sp[1].o0, sp[1].o1, sp[1].o2, sp[1].o3};
    int o2[4] = {sp[2].o0, sp[2].o1, sp[2].o2, sp[2].o3};

    short8v y0[4][2], y1[4][2], y2[4][2];
    // stage scale 0 + scale 1 loads
    #pragma unroll
    for (int cr = 0; cr < 4; cr++) {
        y0[cr][0] = *(const short8v*)(yf + o0[cr]);
        y0[cr][1] = *(const short8v*)(yf + o0[cr] + 8);
    }
    #pragma unroll
    for (int cr = 0; cr < 4; cr++) {
        y1[cr][0] = *(const short8v*)(yf + o1[cr]);
        y1[cr][1] = *(const short8v*)(yf + o1[cr] + 8);
    }

    float xs[16];
    #pragma unroll
    for (int e = 0; e < 8; e++) { xs[e] = bf2f(xv0[e]); xs[8 + e] = bf2f(xv1[e]); }

    float ac[3][4];
    #pragma unroll
    for (int s = 0; s < 3; s++)
        #pragma unroll
        for (int cr = 0; cr < 4; cr++) ac[s][cr] = 0.f;

    // compute scale 0
    #pragma unroll
    for (int cr = 0; cr < 4; cr++)
        #pragma unroll
        for (int i = 0; i < 2; i++)
            #pragma unroll
            for (int e = 0; e < 8; e++)
                ac[0][cr] = fmaf(xs[i * 8 + e], bf2f(y0[cr][i][e]), ac[0][cr]);
    // stage scale 2 loads
    #pragma unroll
    for (int cr = 0; cr < 4; cr++) {
        y2[cr][0] = *(const short8v*)(yf + o2[cr]);
        y2[cr][1] = *(const short8v*)(yf + o2[cr] + 8);
    }
    // compute scale 1
    #pragma unroll
    for (int cr = 0; cr < 4; cr++)
        #pragma unroll
        for (int i = 0; i < 2; i++)
            #pragma unroll
            for (int e = 0; e < 8; e++)
                ac[1][cr] = fmaf(xs[i * 8 + e], bf2f(y1[cr][i][e]), ac[1][cr]);
    // compute scale 2
    #pragma unroll
    for (int cr = 0; cr < 4; cr++)
        #pragma unroll
        for (int i = 0; i < 2; i++)
            #pragma unroll
            for (int e = 0; e < 8; e++)
                ac[2][cr] = fmaf(xs[i * 8 + e], bf2f(y2[cr][i][e]), ac[2][cr]);

    // combine channel quarters: lanes pl, pl+16, pl+32, pl+48
    #pragma unroll
    for (int s = 0; s < 3; s++)
        #pragma unroll
        for (int cr = 0; cr < 4; cr++) {
            float v = ac[s][cr];
            v += __shfl_xor(v, 16, 64);
            v += __shfl_xor(v, 32, 64);
            ac[s][cr] = v;
        }

    if (cq == 0) {
        float c[3];
        c[0] = (ac[0][0] * sp[0].w0 + ac[0][1] * sp[0].w1 + ac[0][2] * sp[0].w2 + ac[0][3] * sp[0].w3) * (1.0f / 64.0f);
        c[1] = (ac[1][0] * sp[1].w0 + ac[1][1] * sp[1].w1 + ac[1][2] * sp[1].w2 + ac[1][3] * sp[1].w3) * (1.0f / 64.0f);
        c[2] = (ac[2][0] * sp[2].w0 + ac[2][1] * sp[2].w1 + ac[2][2] * sp[2].w2 + ac[2][3] * sp[2].w3) * (1.0f / 64.0f);
        float avg = (c[0] + c[1] + c[2]) * (1.0f / 3.0f);
        float mx = fmaxf(c[0], fmaxf(c[1], c[2]));
        float d0 = c[0] - avg, d1 = c[1] - avg, d2 = c[2] - avg;
        float var = (d0 * d0 + d1 * d1 + d2 * d2) * 0.5f;   // ddof=1
        stats[(size_t)n * 4096 + hw] = avg;
        stats[131072 + (size_t)n * 4096 + hw] = mx;
        stats[262144 + (size_t)n * 4096 + hw] = var;
    }
}

// ---------- per-pixel feat multiplier A = sigmoid(avg*attn)-0.5 ----------
__device__ __forceinline__ float attn_val(const float* __restrict__ stats, int n, int hw,
                                          const float* __restrict__ cfw1,
                                          const float* __restrict__ cfw2)
{
    int h = hw >> 6, w = hw & 63;
    const float* avg = stats + (size_t)n * 4096;
    const float* mx  = stats + 131072 + (size_t)n * 4096;
    const float* var = stats + 262144 + (size_t)n * 4096;
    float s = 0.f;
    #pragma unroll
    for (int k = 0; k < 9; k++) {
        int kh = k / 3 - 1, kw = k - (k / 3) * 3 - 1;
        int yy = h + kh, xx = w + kw;
        if (yy >= 0 && yy < 64 && xx >= 0 && xx < 64) {
            int p = yy * 64 + xx;
            s += avg[p] * cfw1[k] + mx[p] * cfw1[9 + k] + var[p] * cfw2[k];
        }
    }
    float attn = sigmoidf_(s);
    return sigmoidf_(avg[hw] * attn) - 0.5f;
}

// ---------- final: channel-split (thread = pixel x channel-half), batched gathers ----------
// grid 1024 x 256: gid0 = n(5b) | ch(1b) | hw(12b)
__global__ __launch_bounds__(256) void k_final(const __hip_bfloat16* __restrict__ xT,
                                               const float* __restrict__ off_l,
                                               const float* __restrict__ off_r,
                                               const float* __restrict__ stats_l,
                                               const float* __restrict__ stats_r,
                                               const float* __restrict__ cfw1,
                                               const float* __restrict__ cfw2,
                                               const float* __restrict__ agg,
                                               const float* __restrict__ backw,
                                               const float* __restrict__ fusw,
                                               float* __restrict__ out)
{
    int gid0 = blockIdx.x * 256 + threadIdx.x;   // 262144
    int hw = gid0 & 4095;
    int ch = (gid0 >> 12) & 1;
    int n = gid0 >> 13;
    int b = n >> 4, t = n & 15;
    int tl = min(t + 1, 15), tr = max(t - 1, 0);
    int nl = b * 16 + tl, nr = b * 16 + tr;
    int h = hw >> 6, w = hw & 63;
    int cc0 = ch * 32;

    float oxl = off_l[((size_t)n * 6 + 0) * 4096 + hw];
    float oyl = off_l[((size_t)n * 6 + 1) * 4096 + hw];
    float oxr = off_r[((size_t)n * 6 + 0) * 4096 + hw];
    float oyr = off_r[((size_t)n * 6 + 1) * 4096 + hw];
    Samp sl = make_samp(oxl, oyl, w, h);
    Samp sr = make_samp(oxr, oyr, w, h);

    const __hip_bfloat16* lf = xT + (size_t)nl * 270336 + cc0;
    const __hip_bfloat16* rf = xT + (size_t)nr * 270336 + cc0;

    // issue all 32 corner loads up front (16 left + 16 right)
    short8v lv[4][4], rv[4][4];
    #pragma unroll
    for (int i = 0; i < 4; i++) {
        lv[0][i] = *(const short8v*)(lf + sl.o0 + 8 * i);
        lv[1][i] = *(const short8v*)(lf + sl.o1 + 8 * i);
        lv[2][i] = *(const short8v*)(lf + sl.o2 + 8 * i);
        lv[3][i] = *(const short8v*)(lf + sl.o3 + 8 * i);
        rv[0][i] = *(const short8v*)(rf + sr.o0 + 8 * i);
        rv[1][i] = *(const short8v*)(rf + sr.o1 + 8 * i);
        rv[2][i] = *(const short8v*)(rf + sr.o2 + 8 * i);
        rv[3][i] = *(const short8v*)(rf + sr.o3 + 8 * i);
    }

    float Al = attn_val(stats_l, n, hw, cfw1, cfw2) * fusw[0];
    float Ar = attn_val(stats_r, n, hw, cfw1, cfw2) * fusw[1];

    float ag0 = agg[((size_t)(b * 4 + 0) * 16 + t) * 4096 + hw];
    float ag1 = agg[((size_t)(b * 4 + 1) * 16 + t) * 4096 + hw];
    float ag2 = agg[((size_t)(b * 4 + 2) * 16 + t) * 4096 + hw];
    float ag3 = agg[((size_t)(b * 4 + 3) * 16 + t) * 4096 + hw];

    #pragma unroll
    for (int i = 0; i < 4; i++) {
        #pragma unroll
        for (int e = 0; e < 8; e++) {
            int c = cc0 + i * 8 + e;
            float wl = sl.w0 * bf2f(lv[0][i][e]) + sl.w1 * bf2f(lv[1][i][e])
                     + sl.w2 * bf2f(lv[2][i][e]) + sl.w3 * bf2f(lv[3][i][e]);
            float wr = sr.w0 * bf2f(rv[0][i][e]) + sr.w1 * bf2f(rv[1][i][e])
                     + sr.w2 * bf2f(rv[2][i][e]) + sr.w3 * bf2f(rv[3][i][e]);
            float lt = sigmoidf_(ag0 * backw[c * 4 + 0] + ag1 * backw[c * 4 + 1]
                               + ag2 * backw[c * 4 + 2] + ag3 * backw[c * 4 + 3]) - 0.5f;
            __builtin_nontemporal_store((wl * Al + wr * Ar) * lt,
                                        &out[(((size_t)b * 64 + c) * 16 + t) * 4096 + hw]);
        }
    }
}

extern "C" void kernel_launch(void* const* d_in, const int* in_sizes, int n_in,
                              void* d_out, int out_size, void* d_ws, size_t ws_size,
                              hipStream_t stream)
{
    const float* x     = (const float*)d_in[0];
    const float* lw1   = (const float*)d_in[1];
    const float* lb1   = (const float*)d_in[2];
    const float* lw2   = (const float*)d_in[3];
    const float* lb2   = (const float*)d_in[4];
    const float* rw1   = (const float*)d_in[5];
    const float* rb1   = (const float*)d_in[6];
    const float* rw2   = (const float*)d_in[7];
    const float* rb2   = (const float*)d_in[8];
    const float* cfw1  = (const float*)d_in[9];
    const float* cfw2  = (const float*)d_in[10];
    const float* downw = (const float*)d_in[11];
    const float* sa1w  = (const float*)d_in[12];
    const float* sa1b  = (const float*)d_in[13];
    const float* sa2w  = (const float*)d_in[14];
    const float* sa2b  = (const float*)d_in[15];
    const float* sa3w  = (const float*)d_in[16];
    const float* sa3b  = (const float*)d_in[17];
    const float* aggw  = (const float*)d_in[18];
    const float* backw = (const float*)d_in[19];
    const float* fusw  = (const float*)d_in[20];
    float* out = (float*)d_out;

    // fp32 region
    float* ws      = (float*)d_ws;
    float* x_agg   = ws;                    // 524288 f
    float* agg     = x_agg + 524288;        // 524288 f
    float* off_l   = agg + 524288;          // 786432 f
    float* off_r   = off_l + 786432;        // 786432 f
    float* stats_l = off_r + 786432;        // 393216 f
    float* stats_r = stats_l + 393216;      // 393216 f
    // bf16 region
    __hip_bfloat16* hidden  = (__hip_bfloat16*)(stats_r + 393216); // 8650752
    __hip_bfloat16* xT      = hidden + HID_ELEMS;                  // 8650752
    __hip_bfloat16* Wmisc   = xT + HID_ELEMS;                      // 170112
    __hip_bfloat16* Wb      = Wmisc;                 // conv1 weights (swizzled), both sides
    __hip_bfloat16* zrow    = Wmisc + 147456;        // 4224 zeros
    __hip_bfloat16* W2bL    = Wmisc + 151680;        // 9216 (W2bR follows contiguously)
    __hip_bfloat16* hidden2 = Wmisc + 170112;        // 8650752 (only if ws allows)

    // merged path needs hidden2: total 65,876,224 bytes
    const size_t need_merged = 65876224ULL;
    const bool merged = (ws_size >= need_merged);
    const size_t hid_stride = merged ? (size_t)(hidden2 - hidden) : 0;

    k_prep_x<<<2048, 256, 0, stream>>>(x, downw, lw1, rw1, lw2, rw2, xT, x_agg, Wmisc);

    k_agg<<<2048, 256, 0, stream>>>(x_agg, sa1w, sa1b, sa2w, sa2b, sa3w, sa3b, aggw, agg);

    if (merged) {
        k_conv1_mfma<<<1024, 512, 0, stream>>>(xT, Wb, zrow, lb1, rb1, hidden, 0, hid_stride, 1);
        k_conv2_mfma<<<1024, 256, 0, stream>>>(hidden, W2bL, zrow, lb2, rb2, off_l, 0, hid_stride);
    } else {
        k_conv1_mfma<<<512, 512, 0, stream>>>(xT, Wb, zrow, lb1, rb1, hidden, 0, 0, 0);
        k_conv2_mfma<<<512, 256, 0, stream>>>(hidden, W2bL, zrow, lb2, rb2, off_l, 0, 0);
        k_conv1_mfma<<<512, 512, 0, stream>>>(xT, Wb, zrow, lb1, rb1, hidden, 1, 0, 0);
        k_conv2_mfma<<<512, 256, 0, stream>>>(hidden, W2bL, zrow, lb2, rb2, off_l, 1, 0);
    }

    // both correlations in one dispatch
    k_corr2<<<4096, 256, 0, stream>>>(xT, off_l, off_r, stats_l, stats_r);

    k_final<<<1024, 256, 0, stream>>>(xT, off_l, off_r, stats_l, stats_r, cfw1, cfw2,
                                      agg, backw, fusw, out);
}

// Round 17
// 254.411 us; speedup vs baseline: 1.0020x; 1.0020x over previous
//
#include <hip/hip_runtime.h>
#include <hip/hip_bf16.h>
#include <math.h>

// Layout constants: B=2, C=64, T=16, H=W=64, S=3, r=4
// x: ((b*64+c)*16+t)*4096 + h*64+w ; frame n in [0,32): b=n>>4, t=n&15
// xT bf16: [n][h 0..63][w' 0..65][c 0..63], w'=w+1, cols 0/65 zero. frame stride 270336, row stride 4224
// hidden bf16: [n][r 0..63][px' 0..65][co 0..63], pad cols zero (written by conv1 epilogue).
// conv1 weights (Wb): per side, per tap: 64co x 128ci bf16, SWIZZLED: el = co*128 + (ci ^ ((co&15)<<3))

typedef __attribute__((ext_vector_type(8))) short short8v;
typedef __attribute__((ext_vector_type(4))) float f32x4;

#define HID_ELEMS 8650752ULL

__device__ __forceinline__ float sigmoidf_(float v) {
    return 1.0f / (1.0f + expf(-v));
}

__device__ __forceinline__ float bf2f(short s) {
    union { unsigned u; float f; } z;
    z.u = ((unsigned)(unsigned short)s) << 16;
    return z.f;
}

// async global->LDS, 16B per lane; LDS base must be wave-uniform (HW adds lane*16)
__device__ __forceinline__ void gll16(const __hip_bfloat16* g, __hip_bfloat16* l) {
    __builtin_amdgcn_global_load_lds((const __attribute__((address_space(1))) unsigned int*)(const void*)g,
                                     (__attribute__((address_space(3))) unsigned int*)(void*)l,
                                     16, 0, 0);
}

// load one tl's 8 A-fragments (2 khalf x {mi0ks0, mi0ks1, mi1ks0, mi1ks1})
__device__ __forceinline__ void load_afrag(const __hip_bfloat16* r0, const __hip_bfloat16* r1,
                                           int abase, short8v* dst) {
    dst[0] = *(const short8v*)(r0 + abase);
    dst[1] = *(const short8v*)(r0 + abase + 32);
    dst[2] = *(const short8v*)(r0 + abase + 1024);
    dst[3] = *(const short8v*)(r0 + abase + 1056);
    dst[4] = *(const short8v*)(r1 + abase);
    dst[5] = *(const short8v*)(r1 + abase + 32);
    dst[6] = *(const short8v*)(r1 + abase + 1024);
    dst[7] = *(const short8v*)(r1 + abase + 1056);
}

// Bilinear sample setup matching reference grid_sample semantics; offsets in xT/channel-last coords.
struct Samp { int o0, o1, o2, o3; float w0, w1, w2, w3; };

__device__ __forceinline__ Samp make_samp(float ox, float oy, int w, int h) {
    float bx = (2.0f * (float)w) / 63.0f - 1.0f;
    float by = (2.0f * (float)h) / 63.0f - 1.0f;
    float vx = bx + ox / 63.0f;
    float vy = by + oy / 63.0f;
    float gx = ((vx + 1.0f) * 64.0f - 1.0f) * 0.5f;
    float gy = ((vy + 1.0f) * 64.0f - 1.0f) * 0.5f;
    float fx = floorf(gx), fy = floorf(gy);
    float wx = gx - fx, wy = gy - fy;
    int x0 = (int)fx, y0 = (int)fy;
    int x1 = x0 + 1, y1 = y0 + 1;
    bool vx0 = (x0 >= 0) && (x0 < 64), vx1 = (x1 >= 0) && (x1 < 64);
    bool vy0 = (y0 >= 0) && (y0 < 64), vy1 = (y1 >= 0) && (y1 < 64);
    int cx0 = min(max(x0, 0), 63), cx1 = min(max(x1, 0), 63);
    int cy0 = min(max(y0, 0), 63), cy1 = min(max(y1, 0), 63);
    Samp s;
    s.o0 = cy0 * 4224 + (cx0 + 1) * 64; s.w0 = (1.0f - wx) * (1.0f - wy) * ((vx0 && vy0) ? 1.0f : 0.0f);
    s.o1 = cy0 * 4224 + (cx1 + 1) * 64; s.w1 = wx * (1.0f - wy) * ((vx1 && vy0) ? 1.0f : 0.0f);
    s.o2 = cy1 * 4224 + (cx0 + 1) * 64; s.w2 = (1.0f - wx) * wy * ((vx0 && vy1) ? 1.0f : 0.0f);
    s.o3 = cy1 * 4224 + (cx1 + 1) * 64; s.w3 = wx * wy * ((vx1 && vy1) ? 1.0f : 0.0f);
    return s;
}

// ---------- prep: x fp32 -> xT bf16 channel-last padded; fused down conv; fused weight prep ----------
__global__ __launch_bounds__(256) void k_prep_x(const float* __restrict__ x,
                                                const float* __restrict__ dw,
                                                const float* __restrict__ wl1,
                                                const float* __restrict__ wr1,
                                                const float* __restrict__ wl2,
                                                const float* __restrict__ wr2,
                                                __hip_bfloat16* __restrict__ xT,
                                                float* __restrict__ xa,
                                                __hip_bfloat16* __restrict__ Wmisc)
{
    int bid = blockIdx.x;          // 2048 = n*64 + h
    int h = bid & 63;
    int n = bid >> 6;
    int b = n >> 4, t = n & 15;
    __shared__ float s[64][65];
    int tid = threadIdx.x;
    for (int idx = tid; idx < 4096; idx += 256) {
        int c = idx >> 6, w = idx & 63;
        s[c][w] = x[(((size_t)b * 64 + c) * 16 + t) * 4096 + h * 64 + w];
    }
    __syncthreads();
    __hip_bfloat16* op = xT + ((size_t)n * 64 + h) * 4224;
    for (int idx = tid; idx < 4224; idx += 256) {
        int wp = idx >> 6, c = idx & 63;
        float v = (wp == 0 || wp == 65) ? 0.f : s[c][wp - 1];
        op[idx] = __float2bfloat16(v);
    }
    // fused down conv: per (g, w) dot over c
    int w = tid & 63, g = tid >> 6;
    float acc = 0.f;
    const float* dwg = dw + g * 64;
    #pragma unroll 8
    for (int c = 0; c < 64; c++) acc = fmaf(s[c][w], dwg[c], acc);
    xa[((size_t)(b * 4 + g) * 16 + t) * 4096 + h * 64 + w] = acc;

    // fused weight prep (blocks 0..664 cover 170112 elements)
    int idx = bid * 256 + tid;
    if (idx < 147456) {
        // conv1: [side][tap 9][co 64][ci 128], ci position XOR-swizzled for LDS bank spread
        int side = (idx >= 73728) ? 1 : 0;
        int i = idx - side * 73728;
        int ci = i & 127;
        int co = (i >> 7) & 63;
        int tap = i >> 13;
        const float* wsrc = side ? wr1 : wl1;
        float v = wsrc[((size_t)co * 128 + ci) * 9 + tap];
        int pos = side * 73728 + tap * 8192 + co * 128 + (ci ^ ((co & 15) << 3));
        Wmisc[pos] = __float2bfloat16(v);
    } else if (idx < 151680) {
        Wmisc[idx] = __float2bfloat16(0.f);      // zero row (4224)
    } else if (idx < 170112) {
        // conv2: [side][tap 9][co 16 pad][ci 64]
        int i2 = idx - 151680;
        int side = i2 / 9216;
        int j = i2 - side * 9216;
        int tap = j >> 10;
        int rem = j & 1023;
        int co = rem >> 6;
        int ci = rem & 63;
        const float* wsrc = side ? wr2 : wl2;
        float v = (co < 6) ? wsrc[((size_t)co * 64 + ci) * 9 + tap] : 0.f;
        Wmisc[idx] = __float2bfloat16(v);
    }
}

// compute one tl slice: 32 MFMAs from A regs + LDS B
#define COMPUTE_TL(TL, A) \
    _Pragma("unroll") \
    for (int khalf = 0; khalf < 2; khalf++) { \
        _Pragma("unroll") \
        for (int ni = 0; ni < 4; ni++) { \
            int rowb = (TL) * 16384 + ni * 4096 + lr * 256; \
            short8v b0  = *(const short8v*)(sbc + (rowb + kx[khalf][0])); \
            short8v b1v = *(const short8v*)(sbc + (rowb + kx[khalf][1])); \
            acc[0][ni] = __builtin_amdgcn_mfma_f32_16x16x32_bf16((A)[khalf*4+0], b0,  acc[0][ni], 0, 0, 0); \
            acc[1][ni] = __builtin_amdgcn_mfma_f32_16x16x32_bf16((A)[khalf*4+2], b0,  acc[1][ni], 0, 0, 0); \
            acc[0][ni] = __builtin_amdgcn_mfma_f32_16x16x32_bf16((A)[khalf*4+1], b1v, acc[0][ni], 0, 0, 0); \
            acc[1][ni] = __builtin_amdgcn_mfma_f32_16x16x32_bf16((A)[khalf*4+3], b1v, acc[1][ni], 0, 0, 0); \
        } \
    }

// ---------- conv1 via MFMA: 128->64 3x3 pad1 + ReLU; 3-tap kh-group LDS staging (best config) ----------
// grid 512 (one side) or 1024 (both); bid = side*512 + n*16 + rq. 512 thr = 8 waves.
__global__ __launch_bounds__(512, 4) void k_conv1_mfma(const __hip_bfloat16* __restrict__ xT,
                                                       const __hip_bfloat16* __restrict__ Wb,
                                                       const __hip_bfloat16* __restrict__ zrow,
                                                       const float* __restrict__ b1l,
                                                       const float* __restrict__ b1r,
                                                       __hip_bfloat16* __restrict__ hidden,
                                                       int side_base, size_t hid_stride)
{
    __shared__ __hip_bfloat16 sB[24576];         // 48KB: 3 taps x (64co x 128ci)

    int bid = blockIdx.x;
    int side = side_base + (bid >> 9);
    int bid2 = bid & 511;
    int rq = bid2 & 15;
    int n = bid2 >> 4;
    int b = n >> 4, t = n & 15;
    int t2 = side ? max(t - 1, 0) : min(t + 1, 15);
    int n2 = b * 16 + t2;

    const __hip_bfloat16* WbS = Wb + (size_t)side * 73728;
    const float* b1 = side ? b1r : b1l;
    __hip_bfloat16* hs = hidden + (size_t)side * hid_stride;

    int tid = threadIdx.x;
    int wv = tid >> 6;
    int lane = tid & 63;
    int r = rq * 4 + (wv & 3);
    int m0 = (wv >> 2) * 32;
    int lr = lane & 15;
    int q = lane >> 4;           // 0..3
    int lk = q << 3;

    const __hip_bfloat16* fA0 = xT + (size_t)n * 270336;
    const __hip_bfloat16* fA1 = xT + (size_t)n2 * 270336;

    f32x4 acc[2][4];
    #pragma unroll
    for (int ni = 0; ni < 4; ni++) {
        float bb = b1[ni * 16 + lr];
        acc[0][ni] = (f32x4){bb, bb, bb, bb};
        acc[1][ni] = (f32x4){bb, bb, bb, bb};
    }

    // swizzled byte offsets within a co-row: (khalf*128 + ks*64 + q*16) ^ (lr<<4)
    int kx[2][2];
    #pragma unroll
    for (int khalf = 0; khalf < 2; khalf++)
        #pragma unroll
        for (int ks = 0; ks < 2; ks++)
            kx[khalf][ks] = ((khalf << 7) + (ks << 6) + (q << 4)) ^ (lr << 4);

    const char* sbc = (const char*)&sB[0];
    int ab0 = (m0 + lr) * 64 + lk;

    short8v A0[8], A1[8], A2[8];

    #pragma unroll
    for (int g = 0; g < 3; g++) {
        int rr = r + g - 1;
        bool ok = (rr >= 0) && (rr < 64);
        const __hip_bfloat16* r0 = ok ? (fA0 + rr * 4224) : zrow;
        const __hip_bfloat16* r1 = ok ? (fA1 + rr * 4224) : zrow;

        __syncthreads();           // previous group fully consumed
        {
            const __hip_bfloat16* wsrc = WbS + (size_t)g * 24576 + wv * 3072 + lane * 8;
            #pragma unroll
            for (int j = 0; j < 6; j++)
                gll16(wsrc + j * 512, &sB[wv * 3072 + j * 512]);
        }
        load_afrag(r0, r1, ab0, A0);            // tl=0 A-loads fly with the staging
        __builtin_amdgcn_sched_barrier(0);
        __syncthreads();                        // vmcnt(0) drains staging + A0 together

        load_afrag(r0, r1, ab0 + 64, A1);       // tl=1: issue now, hide under compute of tl=0
        __builtin_amdgcn_sched_barrier(0);
        COMPUTE_TL(0, A0)
        load_afrag(r0, r1, ab0 + 128, A2);      // tl=2: issue now, hide under compute of tl=1
        __builtin_amdgcn_sched_barrier(0);
        COMPUTE_TL(1, A1)
        COMPUTE_TL(2, A2)
    }

    // store ReLU'd bf16 into padded channel-last hidden (cached stores: conv2 re-reads from L2)
    int pxq = q << 2;
    __hip_bfloat16* hb = hs + (size_t)(n * 64 + r) * 4224;
    #pragma unroll
    for (int mi = 0; mi < 2; mi++) {
        #pragma unroll
        for (int ni = 0; ni < 4; ni++) {
            int co = ni * 16 + lr;
            #pragma unroll
            for (int j = 0; j < 4; j++) {
                int px = m0 + mi * 16 + pxq + j;
                float v = acc[mi][ni][j];
                v = v < 0.f ? 0.f : v;
                hb[(size_t)(px + 1) * 64 + co] = __float2bfloat16(v);
            }
        }
    }
    // zero the pad columns px'=0,65 for this block's 4 rows (one element per thread)
    {
        int row_l = tid >> 7;            // 0..3
        int sel = (tid >> 6) & 1;        // 0 -> px'=0, 1 -> px'=65
        int co = tid & 63;
        hs[(size_t)(n * 64 + rq * 4 + row_l) * 4224 + (sel ? 65 : 0) * 64 + co] = __float2bfloat16(0.f);
    }
}

// ---------- conv2 via MFMA: 64->6 3x3 pad1, M=64 x N=16(6) x K=576 per row ----------
// grid 512 (one side) or 1024 (both); bid = side*512 + n*16 + rq
__global__ __launch_bounds__(256) void k_conv2_mfma(const __hip_bfloat16* __restrict__ hidden,
                                                    const __hip_bfloat16* __restrict__ W2b,
                                                    const __hip_bfloat16* __restrict__ zrow,
                                                    const float* __restrict__ b2l,
                                                    const float* __restrict__ b2r,
                                                    float* __restrict__ off,
                                                    int side_base, size_t hid_stride)
{
    int bid = blockIdx.x;
    int side = side_base + (bid >> 9);
    int bid2 = bid & 511;
    int rq = bid2 & 15;
    int n = bid2 >> 4;
    int tid = threadIdx.x;
    int wv = tid >> 6;
    int lane = tid & 63;
    int r = rq * 4 + wv;
    int lr = lane & 15;
    int lk = (lane >> 4) << 3;

    const __hip_bfloat16* W2bS = W2b + (size_t)side * 9216;
    const float* b2 = side ? b2r : b2l;
    float* offS = off + (size_t)side * 786432;
    const __hip_bfloat16* hbase = hidden + (size_t)side * hid_stride + (size_t)n * 270336;

    float bb = (lr < 6) ? b2[lr] : 0.f;
    f32x4 acc[4];
    #pragma unroll
    for (int mi = 0; mi < 4; mi++) acc[mi] = (f32x4){bb, bb, bb, bb};

    #pragma unroll
    for (int tap = 0; tap < 9; tap++) {
        const int kh = tap / 3, kw = tap - (tap / 3) * 3;
        int rr = r + kh - 1;
        bool ok = (rr >= 0) && (rr < 64);
        const __hip_bfloat16* hr = ok ? (hbase + (size_t)rr * 4224) : zrow;
        const __hip_bfloat16* bw = W2bS + ((size_t)tap * 16 + lr) * 64 + lk;
        short8v b0 = *(const short8v*)(bw);
        short8v b1v = *(const short8v*)(bw + 32);
        #pragma unroll
        for (int mi = 0; mi < 4; mi++) {
            int abase = (mi * 16 + lr + kw) * 64 + lk;
            short8v a0 = *(const short8v*)(hr + abase);
            short8v a1 = *(const short8v*)(hr + abase + 32);
            acc[mi] = __builtin_amdgcn_mfma_f32_16x16x32_bf16(a0, b0, acc[mi], 0, 0, 0);
            acc[mi] = __builtin_amdgcn_mfma_f32_16x16x32_bf16(a1, b1v, acc[mi], 0, 0, 0);
        }
    }
    if (lr < 6) {
        int pxq = (lane >> 4) << 2;
        #pragma unroll
        for (int mi = 0; mi < 4; mi++) {
            #pragma unroll
            for (int j = 0; j < 4; j++) {
                int px = mi * 16 + pxq + j;
                offS[((size_t)n * 6 + lr) * 4096 + r * 64 + px] = acc[mi][j];
            }
        }
    }
}

// ---------- grouped dilated 3D convs, 3 scales, weighted sum (known-good form) ----------
__global__ __launch_bounds__(256) void k_agg(const float* __restrict__ xa,
                                             const float* __restrict__ w1, const float* __restrict__ b1,
                                             const float* __restrict__ w2, const float* __restrict__ b2,
                                             const float* __restrict__ w3, const float* __restrict__ b3,
                                             const float* __restrict__ aw,
                                             float* __restrict__ agg)
{
    int gid = blockIdx.x * 256 + threadIdx.x;   // 524288
    int hw = gid & 4095;
    int rest = gid >> 12;
    int t = rest & 15;
    int g = (rest >> 4) & 3;
    int b = rest >> 6;
    int h = hw >> 6, w = hw & 63;
    const float* base = xa + ((size_t)(b * 4 + g) * 16) * 4096;
    const float* ws0 = w1 + g * 81;
    const float* ws1 = w2 + g * 81;
    const float* ws2 = w3 + g * 81;
    float acc0 = b1[g], acc1 = b2[g], acc2 = b3[g];
    for (int kd = 0; kd < 9; kd++) {
        int d = t + kd - 4;
        if (d < 0 || d > 15) continue;
        const float* fr = base + (size_t)d * 4096;
        #pragma unroll
        for (int kh = 0; kh < 3; kh++) {
            #pragma unroll
            for (int kw = 0; kw < 3; kw++) {
                int widx = kd * 9 + kh * 3 + kw;
                {
                    int yy = h + (kh - 1), xx = w + (kw - 1);
                    if (yy >= 0 && yy < 64 && xx >= 0 && xx < 64)
                        acc0 = fmaf(fr[yy * 64 + xx], ws0[widx], acc0);
                }
                {
                    int yy = h + (kh - 1) * 2, xx = w + (kw - 1) * 2;
                    if (yy >= 0 && yy < 64 && xx >= 0 && xx < 64)
                        acc1 = fmaf(fr[yy * 64 + xx], ws1[widx], acc1);
                }
                {
                    int yy = h + (kh - 1) * 3, xx = w + (kw - 1) * 3;
                    if (yy >= 0 && yy < 64 && xx >= 0 && xx < 64)
                        acc2 = fmaf(fr[yy * 64 + xx], ws2[widx], acc2);
                }
            }
        }
    }
    agg[gid] = acc0 * aw[0] + acc1 * aw[1] + acc2 * aw[2];
}

// ---------- deformable correlation L+R, quarter-split, 2-deep load pipeline ----------
// grid 4096 x 256: wave = 16 pixels x 4 channel-quarters (lane&15 = pixel, lane>>4 = cq)
__global__ __launch_bounds__(256, 4) void k_corr2(const __hip_bfloat16* __restrict__ xT,
                                                  const float* __restrict__ off_l,
                                                  const float* __restrict__ off_r,
                                                  float* __restrict__ stats_l,
                                                  float* __restrict__ stats_r)
{
    int tid = threadIdx.x;
    int wv = tid >> 6;
    int lane = tid & 63;
    int pl = lane & 15;
    int cq = lane >> 4;                          // channel quarter 0..3
    int pidx = blockIdx.x * 64 + wv * 16 + pl;   // 262144 pixel-work items
    int half = pidx >> 17;                       // 0 = left(+1), 1 = right(-1)
    int gid = pidx & 131071;
    const float* off = half ? off_r : off_l;
    float* stats = half ? stats_r : stats_l;

    int hw = gid & 4095;
    int n = gid >> 12;
    int b = n >> 4, t = n & 15;
    int t2 = half ? max(t - 1, 0) : min(t + 1, 15);
    int n2 = b * 16 + t2;
    int h = hw >> 6, w = hw & 63;
    int cc0 = cq * 16;

    const __hip_bfloat16* xf = xT + (size_t)n * 270336 + h * 4224 + (w + 1) * 64 + cc0;
    const __hip_bfloat16* yf = xT + (size_t)n2 * 270336 + cc0;

    Samp sp[3];
    #pragma unroll
    for (int s = 0; s < 3; s++) {
        float ox = off[((size_t)n * 6 + 2 * s) * 4096 + hw];
        float oy = off[((size_t)n * 6 + 2 * s + 1) * 4096 + hw];
        sp[s] = make_samp(ox, oy, w, h);
    }

    // x fragment
    short8v xv0 = *(const short8v*)(xf);
    short8v xv1 = *(const short8v*)(xf + 8);

    int o0[4] = {sp[0].o0, sp[0].o1, sp[0].o2, sp[0].o3};
    int o1[4] = {sp[1].o0, sp[1].o1, sp[1].o2, sp[1].o3};
    int o2[4] = {sp[2].o0, sp[2].o1, sp[2].o2, sp[2].o3};

    short8v y0[4][2], y1[4][2], y2[4][2];
    // stage scale 0 + scale 1 loads
    #pragma unroll
    for (int cr = 0; cr < 4; cr++) {
        y0[cr][0] = *(const short8v*)(yf + o0[cr]);
        y0[cr][1] = *(const short8v*)(yf + o0[cr] + 8);
    }
    #pragma unroll
    for (int cr = 0; cr < 4; cr++) {
        y1[cr][0] = *(const short8v*)(yf + o1[cr]);
        y1[cr][1] = *(const short8v*)(yf + o1[cr] + 8);
    }

    float xs[16];
    #pragma unroll
    for (int e = 0; e < 8; e++) { xs[e] = bf2f(xv0[e]); xs[8 + e] = bf2f(xv1[e]); }

    float ac[3][4];
    #pragma unroll
    for (int s = 0; s < 3; s++)
        #pragma unroll
        for (int cr = 0; cr < 4; cr++) ac[s][cr] = 0.f;

    // compute scale 0
    #pragma unroll
    for (int cr = 0; cr < 4; cr++)
        #pragma unroll
        for (int i = 0; i < 2; i++)
            #pragma unroll
            for (int e = 0; e < 8; e++)
                ac[0][cr] = fmaf(xs[i * 8 + e], bf2f(y0[cr][i][e]), ac[0][cr]);
    // stage scale 2 loads
    #pragma unroll
    for (int cr = 0; cr < 4; cr++) {
        y2[cr][0] = *(const short8v*)(yf + o2[cr]);
        y2[cr][1] = *(const short8v*)(yf + o2[cr] + 8);
    }
    // compute scale 1
    #pragma unroll
    for (int cr = 0; cr < 4; cr++)
        #pragma unroll
        for (int i = 0; i < 2; i++)
            #pragma unroll
            for (int e = 0; e < 8; e++)
                ac[1][cr] = fmaf(xs[i * 8 + e], bf2f(y1[cr][i][e]), ac[1][cr]);
    // compute scale 2
    #pragma unroll
    for (int cr = 0; cr < 4; cr++)
        #pragma unroll
        for (int i = 0; i < 2; i++)
            #pragma unroll
            for (int e = 0; e < 8; e++)
                ac[2][cr] = fmaf(xs[i * 8 + e], bf2f(y2[cr][i][e]), ac[2][cr]);

    // combine channel quarters: lanes pl, pl+16, pl+32, pl+48
    #pragma unroll
    for (int s = 0; s < 3; s++)
        #pragma unroll
        for (int cr = 0; cr < 4; cr++) {
            float v = ac[s][cr];
            v += __shfl_xor(v, 16, 64);
            v += __shfl_xor(v, 32, 64);
            ac[s][cr] = v;
        }

    if (cq == 0) {
        float c[3];
        c[0] = (ac[0][0] * sp[0].w0 + ac[0][1] * sp[0].w1 + ac[0][2] * sp[0].w2 + ac[0][3] * sp[0].w3) * (1.0f / 64.0f);
        c[1] = (ac[1][0] * sp[1].w0 + ac[1][1] * sp[1].w1 + ac[1][2] * sp[1].w2 + ac[1][3] * sp[1].w3) * (1.0f / 64.0f);
        c[2] = (ac[2][0] * sp[2].w0 + ac[2][1] * sp[2].w1 + ac[2][2] * sp[2].w2 + ac[2][3] * sp[2].w3) * (1.0f / 64.0f);
        float avg = (c[0] + c[1] + c[2]) * (1.0f / 3.0f);
        float mx = fmaxf(c[0], fmaxf(c[1], c[2]));
        float d0 = c[0] - avg, d1 = c[1] - avg, d2 = c[2] - avg;
        float var = (d0 * d0 + d1 * d1 + d2 * d2) * 0.5f;   // ddof=1
        stats[(size_t)n * 4096 + hw] = avg;
        stats[131072 + (size_t)n * 4096 + hw] = mx;
        stats[262144 + (size_t)n * 4096 + hw] = var;
    }
}

// ---------- per-pixel feat multiplier A = sigmoid(avg*attn)-0.5 ----------
__device__ __forceinline__ float attn_val(const float* __restrict__ stats, int n, int hw,
                                          const float* __restrict__ cfw1,
                                          const float* __restrict__ cfw2)
{
    int h = hw >> 6, w = hw & 63;
    const float* avg = stats + (size_t)n * 4096;
    const float* mx  = stats + 131072 + (size_t)n * 4096;
    const float* var = stats + 262144 + (size_t)n * 4096;
    float s = 0.f;
    #pragma unroll
    for (int k = 0; k < 9; k++) {
        int kh = k / 3 - 1, kw = k - (k / 3) * 3 - 1;
        int yy = h + kh, xx = w + kw;
        if (yy >= 0 && yy < 64 && xx >= 0 && xx < 64) {
            int p = yy * 64 + xx;
            s += avg[p] * cfw1[k] + mx[p] * cfw1[9 + k] + var[p] * cfw2[k];
        }
    }
    float attn = sigmoidf_(s);
    return sigmoidf_(avg[hw] * attn) - 0.5f;
}

// ---------- final: channel-split (thread = pixel x channel-half), batched gathers ----------
// grid 1024 x 256: gid0 = n(5b) | ch(1b) | hw(12b)
__global__ __launch_bounds__(256) void k_final(const __hip_bfloat16* __restrict__ xT,
                                               const float* __restrict__ off_l,
                                               const float* __restrict__ off_r,
                                               const float* __restrict__ stats_l,
                                               const float* __restrict__ stats_r,
                                               const float* __restrict__ cfw1,
                                               const float* __restrict__ cfw2,
                                               const float* __restrict__ agg,
                                               const float* __restrict__ backw,
                                               const float* __restrict__ fusw,
                                               float* __restrict__ out)
{
    int gid0 = blockIdx.x * 256 + threadIdx.x;   // 262144
    int hw = gid0 & 4095;
    int ch = (gid0 >> 12) & 1;
    int n = gid0 >> 13;
    int b = n >> 4, t = n & 15;
    int tl = min(t + 1, 15), tr = max(t - 1, 0);
    int nl = b * 16 + tl, nr = b * 16 + tr;
    int h = hw >> 6, w = hw & 63;
    int cc0 = ch * 32;

    float oxl = off_l[((size_t)n * 6 + 0) * 4096 + hw];
    float oyl = off_l[((size_t)n * 6 + 1) * 4096 + hw];
    float oxr = off_r[((size_t)n * 6 + 0) * 4096 + hw];
    float oyr = off_r[((size_t)n * 6 + 1) * 4096 + hw];
    Samp sl = make_samp(oxl, oyl, w, h);
    Samp sr = make_samp(oxr, oyr, w, h);

    const __hip_bfloat16* lf = xT + (size_t)nl * 270336 + cc0;
    const __hip_bfloat16* rf = xT + (size_t)nr * 270336 + cc0;

    // issue all 32 corner loads up front (16 left + 16 right)
    short8v lv[4][4], rv[4][4];
    #pragma unroll
    for (int i = 0; i < 4; i++) {
        lv[0][i] = *(const short8v*)(lf + sl.o0 + 8 * i);
        lv[1][i] = *(const short8v*)(lf + sl.o1 + 8 * i);
        lv[2][i] = *(const short8v*)(lf + sl.o2 + 8 * i);
        lv[3][i] = *(const short8v*)(lf + sl.o3 + 8 * i);
        rv[0][i] = *(const short8v*)(rf + sr.o0 + 8 * i);
        rv[1][i] = *(const short8v*)(rf + sr.o1 + 8 * i);
        rv[2][i] = *(const short8v*)(rf + sr.o2 + 8 * i);
        rv[3][i] = *(const short8v*)(rf + sr.o3 + 8 * i);
    }

    float Al = attn_val(stats_l, n, hw, cfw1, cfw2) * fusw[0];
    float Ar = attn_val(stats_r, n, hw, cfw1, cfw2) * fusw[1];

    float ag0 = agg[((size_t)(b * 4 + 0) * 16 + t) * 4096 + hw];
    float ag1 = agg[((size_t)(b * 4 + 1) * 16 + t) * 4096 + hw];
    float ag2 = agg[((size_t)(b * 4 + 2) * 16 + t) * 4096 + hw];
    float ag3 = agg[((size_t)(b * 4 + 3) * 16 + t) * 4096 + hw];

    #pragma unroll
    for (int i = 0; i < 4; i++) {
        #pragma unroll
        for (int e = 0; e < 8; e++) {
            int c = cc0 + i * 8 + e;
            float wl = sl.w0 * bf2f(lv[0][i][e]) + sl.w1 * bf2f(lv[1][i][e])
                     + sl.w2 * bf2f(lv[2][i][e]) + sl.w3 * bf2f(lv[3][i][e]);
            float wr = sr.w0 * bf2f(rv[0][i][e]) + sr.w1 * bf2f(rv[1][i][e])
                     + sr.w2 * bf2f(rv[2][i][e]) + sr.w3 * bf2f(rv[3][i][e]);
            float lt = sigmoidf_(ag0 * backw[c * 4 + 0] + ag1 * backw[c * 4 + 1]
                               + ag2 * backw[c * 4 + 2] + ag3 * backw[c * 4 + 3]) - 0.5f;
            __builtin_nontemporal_store((wl * Al + wr * Ar) * lt,
                                        &out[(((size_t)b * 64 + c) * 16 + t) * 4096 + hw]);
        }
    }
}

extern "C" void kernel_launch(void* const* d_in, const int* in_sizes, int n_in,
                              void* d_out, int out_size, void* d_ws, size_t ws_size,
                              hipStream_t stream)
{
    const float* x     = (const float*)d_in[0];
    const float* lw1   = (const float*)d_in[1];
    const float* lb1   = (const float*)d_in[2];
    const float* lw2   = (const float*)d_in[3];
    const float* lb2   = (const float*)d_in[4];
    const float* rw1   = (const float*)d_in[5];
    const float* rb1   = (const float*)d_in[6];
    const float* rw2   = (const float*)d_in[7];
    const float* rb2   = (const float*)d_in[8];
    const float* cfw1  = (const float*)d_in[9];
    const float* cfw2  = (const float*)d_in[10];
    const float* downw = (const float*)d_in[11];
    const float* sa1w  = (const float*)d_in[12];
    const float* sa1b  = (const float*)d_in[13];
    const float* sa2w  = (const float*)d_in[14];
    const float* sa2b  = (const float*)d_in[15];
    const float* sa3w  = (const float*)d_in[16];
    const float* sa3b  = (const float*)d_in[17];
    const float* aggw  = (const float*)d_in[18];
    const float* backw = (const float*)d_in[19];
    const float* fusw  = (const float*)d_in[20];
    float* out = (float*)d_out;

    // fp32 region
    float* ws      = (float*)d_ws;
    float* x_agg   = ws;                    // 524288 f
    float* agg     = x_agg + 524288;        // 524288 f
    float* off_l   = agg + 524288;          // 786432 f
    float* off_r   = off_l + 786432;        // 786432 f
    float* stats_l = off_r + 786432;        // 393216 f
    float* stats_r = stats_l + 393216;      // 393216 f
    // bf16 region
    __hip_bfloat16* hidden  = (__hip_bfloat16*)(stats_r + 393216); // 8650752
    __hip_bfloat16* xT      = hidden + HID_ELEMS;                  // 8650752
    __hip_bfloat16* Wmisc   = xT + HID_ELEMS;                      // 170112
    __hip_bfloat16* Wb      = Wmisc;                 // conv1 weights (swizzled), both sides
    __hip_bfloat16* zrow    = Wmisc + 147456;        // 4224 zeros
    __hip_bfloat16* W2bL    = Wmisc + 151680;        // 9216 (W2bR follows contiguously)
    __hip_bfloat16* hidden2 = Wmisc + 170112;        // 8650752 (only if ws allows)

    // merged path needs hidden2: total 65,876,224 bytes
    const size_t need_merged = 65876224ULL;
    const bool merged = (ws_size >= need_merged);
    const size_t hid_stride = merged ? (size_t)(hidden2 - hidden) : 0;

    k_prep_x<<<2048, 256, 0, stream>>>(x, downw, lw1, rw1, lw2, rw2, xT, x_agg, Wmisc);

    k_agg<<<2048, 256, 0, stream>>>(x_agg, sa1w, sa1b, sa2w, sa2b, sa3w, sa3b, aggw, agg);

    if (merged) {
        k_conv1_mfma<<<1024, 512, 0, stream>>>(xT, Wb, zrow, lb1, rb1, hidden, 0, hid_stride);
        k_conv2_mfma<<<1024, 256, 0, stream>>>(hidden, W2bL, zrow, lb2, rb2, off_l, 0, hid_stride);
    } else {
        k_conv1_mfma<<<512, 512, 0, stream>>>(xT, Wb, zrow, lb1, rb1, hidden, 0, 0);
        k_conv2_mfma<<<512, 256, 0, stream>>>(hidden, W2bL, zrow, lb2, rb2, off_l, 0, 0);
        k_conv1_mfma<<<512, 512, 0, stream>>>(xT, Wb, zrow, lb1, rb1, hidden, 1, 0);
        k_conv2_mfma<<<512, 256, 0, stream>>>(hidden, W2bL, zrow, lb2, rb2, off_l, 1, 0);
    }

    // both correlations in one dispatch
    k_corr2<<<4096, 256, 0, stream>>>(xT, off_l, off_r, stats_l, stats_r);

    k_final<<<1024, 256, 0, stream>>>(xT, off_l, off_r, stats_l, stats_r, cfw1, cfw2,
                                      agg, backw, fusw, out);
}